// Round 1
// 3263.003 us; speedup vs baseline: 1.1240x; 1.1240x over previous
//
#include <hip/hip_runtime.h>
#include <math.h>

#define L_   8
#define D_   1024
#define H_   16
#define HD_  64
#define DFF_ 4096
#define V_   50257
#define T_   2048
#define B_   2
#define M_   (B_*T_)

typedef __attribute__((ext_vector_type(8))) short short8;
typedef __attribute__((ext_vector_type(4))) float f4;
typedef __attribute__((ext_vector_type(4))) unsigned short us4;

#define GLOAD16(gp, lp) \
  __builtin_amdgcn_global_load_lds((__attribute__((address_space(1))) void*)(gp), \
                                   (__attribute__((address_space(3))) void*)(lp), 16, 0, 0)

__device__ __forceinline__ unsigned short f2bf(float f) {
  union { float f; unsigned u; } c; c.f = f;
  return (unsigned short)((c.u + 0x7fffu + ((c.u >> 16) & 1u)) >> 16);
}

// ---------------- fp32 -> bf16 weight conversion ----------------
__global__ __launch_bounds__(256) void cvt_kernel(const float* __restrict__ s,
                                                  unsigned short* __restrict__ d, int n) {
  int i = (blockIdx.x * 256 + threadIdx.x) * 4;
  const int stride = gridDim.x * 256 * 4;
  for (; i < n; i += stride) {
    f4 f = *(const f4*)(s + i);
    us4 o;
    o.x = f2bf(f.x); o.y = f2bf(f.y); o.z = f2bf(f.z); o.w = f2bf(f.w);
    *(us4*)(d + i) = o;
  }
}

// ---------------- embedding ----------------
__global__ __launch_bounds__(256) void embed_kernel(const int* __restrict__ x,
    const float* __restrict__ wemb, const float* __restrict__ pos, float* __restrict__ h) {
  const int m = blockIdx.x;
  const int t = m & (T_ - 1);
  const int idx = x[m];
  const int d = threadIdx.x * 4;
  f4 a = *(const f4*)(wemb + (size_t)idx * D_ + d);
  f4 b = *(const f4*)(pos + (size_t)t * D_ + d);
  a = a + b;
  *(f4*)(h + (size_t)m * D_ + d) = a;
}

// ---------------- layernorm (ddof=1, std+eps) -> bf16 ----------------
__global__ __launch_bounds__(256) void ln_kernel(const float* __restrict__ h,
    const float* __restrict__ sc, const float* __restrict__ sh,
    unsigned short* __restrict__ out) {
  const int row = blockIdx.x, tid = threadIdx.x;
  f4 x = *(const f4*)(h + (size_t)row * D_ + tid * 4);
  float s1 = x.x + x.y + x.z + x.w;
  float s2 = x.x * x.x + x.y * x.y + x.z * x.z + x.w * x.w;
#pragma unroll
  for (int off = 32; off > 0; off >>= 1) {
    s1 += __shfl_down(s1, off);
    s2 += __shfl_down(s2, off);
  }
  __shared__ float r1[4], r2[4];
  if ((tid & 63) == 0) { r1[tid >> 6] = s1; r2[tid >> 6] = s2; }
  __syncthreads();
  float t1 = r1[0] + r1[1] + r1[2] + r1[3];
  float t2 = r2[0] + r2[1] + r2[2] + r2[3];
  float mean = t1 * (1.0f / D_);
  float var = fmaxf((t2 - t1 * mean) * (1.0f / (D_ - 1)), 0.0f);
  float inv = 1.0f / (sqrtf(var) + 1e-5f);
  f4 s = *(const f4*)(sc + tid * 4);
  f4 b = *(const f4*)(sh + tid * 4);
  us4 o;
  o.x = f2bf(s.x * ((x.x - mean) * inv) + b.x);
  o.y = f2bf(s.y * ((x.y - mean) * inv) + b.y);
  o.z = f2bf(s.z * ((x.z - mean) * inv) + b.z);
  o.w = f2bf(s.w * ((x.w - mean) * inv) + b.w);
  *(us4*)(out + (size_t)row * D_ + tid * 4) = o;
}

// final LN: only the last token of each batch, fp32 out [2][D]
__global__ __launch_bounds__(256) void ln_final_kernel(const float* __restrict__ h,
    const float* __restrict__ sc, const float* __restrict__ sh, float* __restrict__ out) {
  const int b = blockIdx.x, tid = threadIdx.x;
  const int row = b * T_ + (T_ - 1);
  f4 x = *(const f4*)(h + (size_t)row * D_ + tid * 4);
  float s1 = x.x + x.y + x.z + x.w;
  float s2 = x.x * x.x + x.y * x.y + x.z * x.z + x.w * x.w;
#pragma unroll
  for (int off = 32; off > 0; off >>= 1) {
    s1 += __shfl_down(s1, off);
    s2 += __shfl_down(s2, off);
  }
  __shared__ float r1[4], r2[4];
  if ((tid & 63) == 0) { r1[tid >> 6] = s1; r2[tid >> 6] = s2; }
  __syncthreads();
  float t1 = r1[0] + r1[1] + r1[2] + r1[3];
  float t2 = r2[0] + r2[1] + r2[2] + r2[3];
  float mean = t1 * (1.0f / D_);
  float var = fmaxf((t2 - t1 * mean) * (1.0f / (D_ - 1)), 0.0f);
  float inv = 1.0f / (sqrtf(var) + 1e-5f);
  f4 s = *(const f4*)(sc + tid * 4);
  f4 bb = *(const f4*)(sh + tid * 4);
  f4 o;
  o.x = s.x * ((x.x - mean) * inv) + bb.x;
  o.y = s.y * ((x.y - mean) * inv) + bb.y;
  o.z = s.z * ((x.z - mean) * inv) + bb.z;
  o.w = s.w * ((x.w - mean) * inv) + bb.w;
  *(f4*)(out + (size_t)b * D_ + tid * 4) = o;
}

// ---------------- GEMM: C[M,N] = A[M,K] @ W[N,K]^T (+epilogue) ----------------
#define EP_QKV 0
#define EP_RES 1
#define EP_GELU 2

template <int MODE>
__global__ __launch_bounds__(256) void gemm_kernel(
    const unsigned short* __restrict__ A,
    const unsigned short* __restrict__ Bq,
    const unsigned short* __restrict__ Bk,
    const unsigned short* __restrict__ Bv,
    const float* __restrict__ bias,
    float* __restrict__ hres,
    unsigned short* __restrict__ out0,
    unsigned short* __restrict__ out1,
    unsigned short* __restrict__ out2,
    int N, int K) {
  __shared__ __attribute__((aligned(16))) unsigned short As[128 * 32];
  __shared__ __attribute__((aligned(16))) unsigned short Bs[128 * 32];
  const int tid = threadIdx.x;
  const int wv = tid >> 6, lane = tid & 63;
  const int quad = lane >> 4, l16 = lane & 15;
  const int bm0 = blockIdx.x * 128;
  int bn0;
  const unsigned short* Bw;
  unsigned short* qout = out0;
  if (MODE == EP_QKV) {
    int sel = blockIdx.y >> 3;
    bn0 = (blockIdx.y & 7) * 128;
    Bw = (sel == 0) ? Bq : ((sel == 1) ? Bk : Bv);
    qout = (sel == 0) ? out0 : ((sel == 1) ? out1 : out2);
  } else {
    bn0 = blockIdx.y * 128;
    Bw = Bq;
  }
  const int wm = (wv & 1) * 64, wn = (wv >> 1) * 64;

  f4 acc[4][4] = {};

  for (int k0 = 0; k0 < K; k0 += 32) {
#pragma unroll
    for (int i = 0; i < 2; i++) {
      int c = i * 256 + tid;
      int row = c >> 2;
      int c4 = (c & 3) ^ (row & 3);  // in-row XOR swizzle (keeps 64B coalescing)
      GLOAD16(A + (size_t)(bm0 + row) * K + k0 + c4 * 8,
              (char*)As + (i * 256 + wv * 64) * 16);
      GLOAD16(Bw + (size_t)(bn0 + row) * K + k0 + c4 * 8,
              (char*)Bs + (i * 256 + wv * 64) * 16);
    }
    __syncthreads();
    short8 af[4], bfr[4];
#pragma unroll
    for (int mt = 0; mt < 4; mt++) {
      int row = wm + mt * 16 + l16;
      af[mt] = *(const short8*)(As + row * 32 + ((quad ^ (row & 3)) * 8));
    }
#pragma unroll
    for (int nt = 0; nt < 4; nt++) {
      int row = wn + nt * 16 + l16;
      bfr[nt] = *(const short8*)(Bs + row * 32 + ((quad ^ (row & 3)) * 8));
    }
#pragma unroll
    for (int mt = 0; mt < 4; mt++)
#pragma unroll
      for (int nt = 0; nt < 4; nt++)
        acc[mt][nt] = __builtin_amdgcn_mfma_f32_16x16x32_bf16(af[mt], bfr[nt], acc[mt][nt], 0, 0, 0);
    __syncthreads();
  }

#pragma unroll
  for (int mt = 0; mt < 4; mt++) {
#pragma unroll
    for (int nt = 0; nt < 4; nt++) {
#pragma unroll
      for (int r = 0; r < 4; r++) {
        int gm = bm0 + wm + mt * 16 + quad * 4 + r;
        int gn = bn0 + wn + nt * 16 + l16;
        float val = acc[mt][nt][r];
        if (MODE == EP_QKV) {
          int b = gm >> 11, t = gm & (T_ - 1);
          int hh = gn >> 6, hd = gn & 63;
          qout[(size_t)((b * H_ + hh) * T_ + t) * HD_ + hd] = f2bf(val);
        } else if (MODE == EP_RES) {
          size_t idx = (size_t)gm * D_ + gn;
          hres[idx] += val + bias[gn];
        } else {  // EP_GELU
          float xg = val + bias[gn];
          float z = 0.7978845608028654f * (xg + 0.044715f * xg * xg * xg);
          float e = __expf(2.0f * z);
          float th = 1.0f - 2.0f / (e + 1.0f);
          out0[(size_t)gm * DFF_ + gn] = f2bf(0.5f * xg * (1.0f + th));
        }
      }
    }
  }
}

// ---------------- V transpose: [B,H,T,HD] -> [B,H,HD,T] ----------------
__global__ __launch_bounds__(256) void vtrans_kernel(const unsigned short* __restrict__ v,
                                                     unsigned short* __restrict__ vt) {
  __shared__ __attribute__((aligned(16))) unsigned short tile[64 * 72];
  const int tid = threadIdx.x;
  const int t0 = blockIdx.x * 64;
  const size_t bh = (size_t)(blockIdx.z * H_ + blockIdx.y);
  const unsigned short* vp = v + bh * T_ * HD_;
#pragma unroll
  for (int i = 0; i < 2; i++) {
    int c = i * 256 + tid;
    int row = c >> 3, c8 = c & 7;
    *(short8*)(tile + row * 72 + c8 * 8) =
        *(const short8*)(vp + (size_t)(t0 + row) * HD_ + c8 * 8);
  }
  __syncthreads();
  unsigned short* op = vt + bh * (size_t)HD_ * T_;
#pragma unroll
  for (int i = 0; i < 2; i++) {
    int c = i * 256 + tid;
    int drow = c >> 3, c8 = c & 7;
    short8 o;
#pragma unroll
    for (int j = 0; j < 8; j++) o[j] = (short)tile[(c8 * 8 + j) * 72 + drow];
    *(short8*)(op + (size_t)drow * T_ + t0 + c8 * 8) = o;
  }
}

// ---------------- flash attention (causal), MFMA, paired q-tiles ----------------
// One K/V-tile processing step for one 64-row q-tile (macro => guaranteed inline,
// all array indices compile-time so everything stays in registers).
#define ATTN_STEP(QF0, QF1, OF, MR, LR, QT)                                        \
  {                                                                                \
    float sv[4][4];                                                                \
    _Pragma("unroll") for (int nt = 0; nt < 4; nt++) {                             \
      int row = nt * 16 + l16;                                                     \
      int p0 = (quad ^ (row & 7)) * 8;                                             \
      int p1 = ((4 + quad) ^ (row & 7)) * 8;                                       \
      short8 kf0 = *(const short8*)(Ks + row * 64 + p0);                           \
      short8 kf1 = *(const short8*)(Ks + row * 64 + p1);                           \
      f4 z = {};                                                                   \
      z = __builtin_amdgcn_mfma_f32_16x16x32_bf16(QF0, kf0, z, 0, 0, 0);           \
      z = __builtin_amdgcn_mfma_f32_16x16x32_bf16(QF1, kf1, z, 0, 0, 0);           \
      _Pragma("unroll") for (int r = 0; r < 4; r++) {                              \
        float s = z[r] * 0.125f;                                                   \
        if (kt == (QT)) {                                                          \
          int col = kb + nt * 16 + l16;                                            \
          int rowg = (QT) * 64 + wv * 16 + quad * 4 + r;                           \
          if (col > rowg) s = -1e30f;                                              \
        }                                                                          \
        sv[nt][r] = s;                                                             \
      }                                                                            \
    }                                                                              \
    float mnew[4], alpha[4];                                                       \
    _Pragma("unroll") for (int r = 0; r < 4; r++) {                                \
      float mx = fmaxf(fmaxf(sv[0][r], sv[1][r]), fmaxf(sv[2][r], sv[3][r]));      \
      mx = fmaxf(mx, __shfl_xor(mx, 1));                                           \
      mx = fmaxf(mx, __shfl_xor(mx, 2));                                           \
      mx = fmaxf(mx, __shfl_xor(mx, 4));                                           \
      mx = fmaxf(mx, __shfl_xor(mx, 8));                                           \
      mnew[r] = fmaxf(MR[r], mx);                                                  \
      alpha[r] = __expf(MR[r] - mnew[r]);                                          \
      MR[r] = mnew[r];                                                             \
    }                                                                              \
    float pv[4][4];                                                                \
    _Pragma("unroll") for (int nt = 0; nt < 4; nt++)                               \
      _Pragma("unroll") for (int r = 0; r < 4; r++)                                \
        pv[nt][r] = __expf(sv[nt][r] - mnew[r]);                                   \
    _Pragma("unroll") for (int r = 0; r < 4; r++) {                                \
      float s = pv[0][r] + pv[1][r] + pv[2][r] + pv[3][r];                         \
      s += __shfl_xor(s, 1);                                                       \
      s += __shfl_xor(s, 2);                                                       \
      s += __shfl_xor(s, 4);                                                       \
      s += __shfl_xor(s, 8);                                                       \
      LR[r] = LR[r] * alpha[r] + s;                                                \
    }                                                                              \
    _Pragma("unroll") for (int nt = 0; nt < 4; nt++) {                             \
      OF[nt][0] *= alpha[0];                                                       \
      OF[nt][1] *= alpha[1];                                                       \
      OF[nt][2] *= alpha[2];                                                       \
      OF[nt][3] *= alpha[3];                                                       \
    }                                                                              \
    _Pragma("unroll") for (int nt = 0; nt < 4; nt++)                               \
      _Pragma("unroll") for (int r = 0; r < 4; r++)                                \
        pw[(quad * 4 + r) * 88 + nt * 16 + l16] = f2bf(pv[nt][r]);                 \
    short8 pf0 = *(const short8*)(pw + l16 * 88 + quad * 8);                       \
    short8 pf1 = *(const short8*)(pw + l16 * 88 + 32 + quad * 8);                  \
    _Pragma("unroll") for (int nt = 0; nt < 4; nt++) {                             \
      int row = nt * 16 + l16;                                                     \
      int p0 = (quad ^ (row & 7)) * 8;                                             \
      int p1 = ((4 + quad) ^ (row & 7)) * 8;                                       \
      short8 vf0 = *(const short8*)(Vs + row * 64 + p0);                           \
      short8 vf1 = *(const short8*)(Vs + row * 64 + p1);                           \
      OF[nt] = __builtin_amdgcn_mfma_f32_16x16x32_bf16(pf0, vf0, OF[nt], 0, 0, 0); \
      OF[nt] = __builtin_amdgcn_mfma_f32_16x16x32_bf16(pf1, vf1, OF[nt], 0, 0, 0); \
    }                                                                              \
  }

// Work-balanced: block bx owns q-tiles (bx, 31-bx) => exactly 33 tile-steps per
// block, 512 uniform blocks (2/CU), K/V tiles staged once and shared by both
// q-tiles while both are active.
__global__ __launch_bounds__(256, 2) void attn_kernel(
    const unsigned short* __restrict__ q,
    const unsigned short* __restrict__ k,
    const unsigned short* __restrict__ vt,
    unsigned short* __restrict__ ctx) {
  __shared__ __attribute__((aligned(16))) unsigned short Ks[64 * 64];
  __shared__ __attribute__((aligned(16))) unsigned short Vs[64 * 64];
  __shared__ __attribute__((aligned(16))) unsigned short Ps[4][16 * 88];
  const int tid = threadIdx.x;
  const int wv = tid >> 6, lane = tid & 63;
  const int quad = lane >> 4, l16 = lane & 15;
  const int bx = blockIdx.x, hh = blockIdx.y, b = blockIdx.z;
  const int qtA = bx, qtB = 31 - bx;  // qtA in [0,16), qtB in [16,32)
  const size_t bh = (size_t)(b * H_ + hh);
  const unsigned short* qp = q + bh * T_ * HD_;
  const unsigned short* kp = k + bh * T_ * HD_;
  const unsigned short* vp = vt + bh * (size_t)HD_ * T_;

  const int qrA = qtA * 64 + wv * 16 + l16;
  const int qrB = qtB * 64 + wv * 16 + l16;
  const short8 qfA0 = *(const short8*)(qp + (size_t)qrA * HD_ + quad * 8);
  const short8 qfA1 = *(const short8*)(qp + (size_t)qrA * HD_ + 32 + quad * 8);
  const short8 qfB0 = *(const short8*)(qp + (size_t)qrB * HD_ + quad * 8);
  const short8 qfB1 = *(const short8*)(qp + (size_t)qrB * HD_ + 32 + quad * 8);

  f4 ofA[4] = {}, ofB[4] = {};
  float mA[4] = {-1e30f, -1e30f, -1e30f, -1e30f}, lA[4] = {0.f, 0.f, 0.f, 0.f};
  float mB[4] = {-1e30f, -1e30f, -1e30f, -1e30f}, lB[4] = {0.f, 0.f, 0.f, 0.f};
  unsigned short* pw = Ps[wv];

  const int nkt = qtB + 1;
  for (int kt = 0; kt < nkt; kt++) {
    const int kb = kt * 64;
#pragma unroll
    for (int i = 0; i < 2; i++) {
      int c = i * 256 + tid;
      int row = c >> 3;
      int c8 = (c & 7) ^ (row & 7);
      GLOAD16(kp + (size_t)(kb + row) * HD_ + c8 * 8, (char*)Ks + (i * 256 + wv * 64) * 16);
      GLOAD16(vp + (size_t)row * T_ + kb + c8 * 8, (char*)Vs + (i * 256 + wv * 64) * 16);
    }
    __syncthreads();
    ATTN_STEP(qfB0, qfB1, ofB, mB, lB, qtB);
    if (kt <= qtA) ATTN_STEP(qfA0, qfA1, ofA, mA, lA, qtA);
    __syncthreads();
  }
#pragma unroll
  for (int nt = 0; nt < 4; nt++) {
#pragma unroll
    for (int r = 0; r < 4; r++) {
      int dcol = hh * HD_ + nt * 16 + l16;
      int rowgB = qtB * 64 + wv * 16 + quad * 4 + r;
      ctx[(size_t)(b * T_ + rowgB) * D_ + dcol] = f2bf(ofB[nt][r] / lB[r]);
      int rowgA = qtA * 64 + wv * 16 + quad * 4 + r;
      ctx[(size_t)(b * T_ + rowgA) * D_ + dcol] = f2bf(ofA[nt][r] / lA[r]);
    }
  }
}

// ---------------- logits GEMV: out[b,v] = hln[b,:] . Wemb[v,:] ----------------
__global__ __launch_bounds__(256) void logits_kernel(const float* __restrict__ wemb,
    const float* __restrict__ hln, float* __restrict__ out) {
  const int tid = threadIdx.x;
  const int wv = tid >> 6, lane = tid & 63;
  const int rbase = blockIdx.x * 32 + wv * 8;
  f4 h0[4], h1[4];
#pragma unroll
  for (int j = 0; j < 4; j++) {
    h0[j] = *(const f4*)(hln + j * 256 + lane * 4);
    h1[j] = *(const f4*)(hln + D_ + j * 256 + lane * 4);
  }
#pragma unroll
  for (int i = 0; i < 8; i++) {
    int r = rbase + i;
    if (r >= V_) return;
    const float* wr = wemb + (size_t)r * D_;
    float a0 = 0.f, a1 = 0.f;
#pragma unroll
    for (int j = 0; j < 4; j++) {
      f4 w4 = *(const f4*)(wr + j * 256 + lane * 4);
      a0 += w4.x * h0[j].x + w4.y * h0[j].y + w4.z * h0[j].z + w4.w * h0[j].w;
      a1 += w4.x * h1[j].x + w4.y * h1[j].y + w4.z * h1[j].z + w4.w * h1[j].w;
    }
#pragma unroll
    for (int off = 32; off > 0; off >>= 1) {
      a0 += __shfl_down(a0, off);
      a1 += __shfl_down(a1, off);
    }
    if (lane == 0) {
      out[r] = a0;
      out[V_ + r] = a1;
    }
  }
}

extern "C" void kernel_launch(void* const* d_in, const int* in_sizes, int n_in,
                              void* d_out, int out_size, void* d_ws, size_t ws_size,
                              hipStream_t stream) {
  (void)in_sizes; (void)n_in; (void)out_size; (void)ws_size;
  const int*   x    = (const int*)  d_in[0];
  const float* Wemb = (const float*)d_in[1];
  const float* pos  = (const float*)d_in[2];
  const float* Wq   = (const float*)d_in[3];
  const float* Wk   = (const float*)d_in[4];
  const float* Wv   = (const float*)d_in[5];
  const float* Wo   = (const float*)d_in[6];
  const float* bo   = (const float*)d_in[7];
  const float* n1s  = (const float*)d_in[8];
  const float* n1b  = (const float*)d_in[9];
  const float* n2s  = (const float*)d_in[10];
  const float* n2b  = (const float*)d_in[11];
  const float* W1   = (const float*)d_in[12];
  const float* b1   = (const float*)d_in[13];
  const float* W2   = (const float*)d_in[14];
  const float* b2   = (const float*)d_in[15];
  const float* fsc  = (const float*)d_in[16];
  const float* fsh  = (const float*)d_in[17];
  float* out = (float*)d_out;

  char* p = (char*)d_ws;
  auto alloc = [&](size_t bytes) -> char* {
    char* r = p;
    p += (bytes + 255) & ~(size_t)255;
    return r;
  };
  unsigned short* wq_b = (unsigned short*)alloc((size_t)L_ * D_ * D_ * 2);
  unsigned short* wk_b = (unsigned short*)alloc((size_t)L_ * D_ * D_ * 2);
  unsigned short* wv_b = (unsigned short*)alloc((size_t)L_ * D_ * D_ * 2);
  unsigned short* wo_b = (unsigned short*)alloc((size_t)L_ * D_ * D_ * 2);
  unsigned short* w1_b = (unsigned short*)alloc((size_t)L_ * DFF_ * D_ * 2);
  unsigned short* w2_b = (unsigned short*)alloc((size_t)L_ * DFF_ * D_ * 2);
  float*          h    = (float*)alloc((size_t)M_ * D_ * 4);
  unsigned short* xn   = (unsigned short*)alloc((size_t)M_ * D_ * 2);
  unsigned short* qb   = (unsigned short*)alloc((size_t)M_ * D_ * 2);
  unsigned short* kb   = (unsigned short*)alloc((size_t)M_ * D_ * 2);
  unsigned short* vb   = (unsigned short*)alloc((size_t)M_ * D_ * 2);
  unsigned short* vtb  = (unsigned short*)alloc((size_t)M_ * D_ * 2);
  unsigned short* ctx  = (unsigned short*)alloc((size_t)M_ * D_ * 2);
  unsigned short* act  = (unsigned short*)alloc((size_t)M_ * DFF_ * 2);
  float*          hln  = (float*)alloc(2 * D_ * 4);

  cvt_kernel<<<2048, 256, 0, stream>>>(Wq, wq_b, L_ * D_ * D_);
  cvt_kernel<<<2048, 256, 0, stream>>>(Wk, wk_b, L_ * D_ * D_);
  cvt_kernel<<<2048, 256, 0, stream>>>(Wv, wv_b, L_ * D_ * D_);
  cvt_kernel<<<2048, 256, 0, stream>>>(Wo, wo_b, L_ * D_ * D_);
  cvt_kernel<<<2048, 256, 0, stream>>>(W1, w1_b, L_ * DFF_ * D_);
  cvt_kernel<<<2048, 256, 0, stream>>>(W2, w2_b, L_ * DFF_ * D_);
  embed_kernel<<<M_, 256, 0, stream>>>(x, Wemb, pos, h);

  for (int l = 0; l < L_; l++) {
    ln_kernel<<<M_, 256, 0, stream>>>(h, n1s + l * D_, n1b + l * D_, xn);
    gemm_kernel<EP_QKV><<<dim3(32, 24), 256, 0, stream>>>(
        xn, wq_b + (size_t)l * D_ * D_, wk_b + (size_t)l * D_ * D_,
        wv_b + (size_t)l * D_ * D_, nullptr, nullptr, qb, kb, vb, D_, D_);
    vtrans_kernel<<<dim3(32, H_, B_), 256, 0, stream>>>(vb, vtb);
    attn_kernel<<<dim3(16, H_, B_), 256, 0, stream>>>(qb, kb, vtb, ctx);
    gemm_kernel<EP_RES><<<dim3(32, 8), 256, 0, stream>>>(
        ctx, wo_b + (size_t)l * D_ * D_, nullptr, nullptr,
        bo + l * D_, h, nullptr, nullptr, nullptr, D_, D_);
    ln_kernel<<<M_, 256, 0, stream>>>(h, n2s + l * D_, n2b + l * D_, xn);
    gemm_kernel<EP_GELU><<<dim3(32, 32), 256, 0, stream>>>(
        xn, w1_b + (size_t)l * DFF_ * D_, nullptr, nullptr,
        b1 + l * DFF_, nullptr, act, nullptr, nullptr, DFF_, D_);
    gemm_kernel<EP_RES><<<dim3(32, 8), 256, 0, stream>>>(
        act, w2_b + (size_t)l * DFF_ * D_, nullptr, nullptr,
        b2 + l * D_, h, nullptr, nullptr, nullptr, D_, DFF_);
  }
  ln_final_kernel<<<2, 256, 0, stream>>>(h, fsc, fsh, hln);
  logits_kernel<<<(V_ + 31) / 32, 256, 0, stream>>>(Wemb, hln, out);
}

// Round 2
// 3036.534 us; speedup vs baseline: 1.2078x; 1.0746x over previous
//
#include <hip/hip_runtime.h>
#include <math.h>

#define L_   8
#define D_   1024
#define H_   16
#define HD_  64
#define DFF_ 4096
#define V_   50257
#define T_   2048
#define B_   2
#define M_   (B_*T_)

typedef __attribute__((ext_vector_type(8))) short short8;
typedef __attribute__((ext_vector_type(4))) float f4;
typedef __attribute__((ext_vector_type(4))) unsigned short us4;

#define GLOAD16(gp, lp) \
  __builtin_amdgcn_global_load_lds((__attribute__((address_space(1))) void*)(gp), \
                                   (__attribute__((address_space(3))) void*)(lp), 16, 0, 0)

__device__ __forceinline__ unsigned short f2bf(float f) {
  union { float f; unsigned u; } c; c.f = f;
  return (unsigned short)((c.u + 0x7fffu + ((c.u >> 16) & 1u)) >> 16);
}

// ---------------- fp32 -> bf16 weight conversion ----------------
__global__ __launch_bounds__(256) void cvt_kernel(const float* __restrict__ s,
                                                  unsigned short* __restrict__ d, int n) {
  int i = (blockIdx.x * 256 + threadIdx.x) * 4;
  const int stride = gridDim.x * 256 * 4;
  for (; i < n; i += stride) {
    f4 f = *(const f4*)(s + i);
    us4 o;
    o.x = f2bf(f.x); o.y = f2bf(f.y); o.z = f2bf(f.z); o.w = f2bf(f.w);
    *(us4*)(d + i) = o;
  }
}

// ---------------- embedding ----------------
__global__ __launch_bounds__(256) void embed_kernel(const int* __restrict__ x,
    const float* __restrict__ wemb, const float* __restrict__ pos, float* __restrict__ h) {
  const int m = blockIdx.x;
  const int t = m & (T_ - 1);
  const int idx = x[m];
  const int d = threadIdx.x * 4;
  f4 a = *(const f4*)(wemb + (size_t)idx * D_ + d);
  f4 b = *(const f4*)(pos + (size_t)t * D_ + d);
  a = a + b;
  *(f4*)(h + (size_t)m * D_ + d) = a;
}

// ---------------- layernorm (ddof=1, std+eps) -> bf16 ----------------
__global__ __launch_bounds__(256) void ln_kernel(const float* __restrict__ h,
    const float* __restrict__ sc, const float* __restrict__ sh,
    unsigned short* __restrict__ out) {
  const int row = blockIdx.x, tid = threadIdx.x;
  f4 x = *(const f4*)(h + (size_t)row * D_ + tid * 4);
  float s1 = x.x + x.y + x.z + x.w;
  float s2 = x.x * x.x + x.y * x.y + x.z * x.z + x.w * x.w;
#pragma unroll
  for (int off = 32; off > 0; off >>= 1) {
    s1 += __shfl_down(s1, off);
    s2 += __shfl_down(s2, off);
  }
  __shared__ float r1[4], r2[4];
  if ((tid & 63) == 0) { r1[tid >> 6] = s1; r2[tid >> 6] = s2; }
  __syncthreads();
  float t1 = r1[0] + r1[1] + r1[2] + r1[3];
  float t2 = r2[0] + r2[1] + r2[2] + r2[3];
  float mean = t1 * (1.0f / D_);
  float var = fmaxf((t2 - t1 * mean) * (1.0f / (D_ - 1)), 0.0f);
  float inv = 1.0f / (sqrtf(var) + 1e-5f);
  f4 s = *(const f4*)(sc + tid * 4);
  f4 b = *(const f4*)(sh + tid * 4);
  us4 o;
  o.x = f2bf(s.x * ((x.x - mean) * inv) + b.x);
  o.y = f2bf(s.y * ((x.y - mean) * inv) + b.y);
  o.z = f2bf(s.z * ((x.z - mean) * inv) + b.z);
  o.w = f2bf(s.w * ((x.w - mean) * inv) + b.w);
  *(us4*)(out + (size_t)row * D_ + tid * 4) = o;
}

// final LN: only the last token of each batch, fp32 out [2][D]
__global__ __launch_bounds__(256) void ln_final_kernel(const float* __restrict__ h,
    const float* __restrict__ sc, const float* __restrict__ sh, float* __restrict__ out) {
  const int b = blockIdx.x, tid = threadIdx.x;
  const int row = b * T_ + (T_ - 1);
  f4 x = *(const f4*)(h + (size_t)row * D_ + tid * 4);
  float s1 = x.x + x.y + x.z + x.w;
  float s2 = x.x * x.x + x.y * x.y + x.z * x.z + x.w * x.w;
#pragma unroll
  for (int off = 32; off > 0; off >>= 1) {
    s1 += __shfl_down(s1, off);
    s2 += __shfl_down(s2, off);
  }
  __shared__ float r1[4], r2[4];
  if ((tid & 63) == 0) { r1[tid >> 6] = s1; r2[tid >> 6] = s2; }
  __syncthreads();
  float t1 = r1[0] + r1[1] + r1[2] + r1[3];
  float t2 = r2[0] + r2[1] + r2[2] + r2[3];
  float mean = t1 * (1.0f / D_);
  float var = fmaxf((t2 - t1 * mean) * (1.0f / (D_ - 1)), 0.0f);
  float inv = 1.0f / (sqrtf(var) + 1e-5f);
  f4 s = *(const f4*)(sc + tid * 4);
  f4 bb = *(const f4*)(sh + tid * 4);
  f4 o;
  o.x = s.x * ((x.x - mean) * inv) + bb.x;
  o.y = s.y * ((x.y - mean) * inv) + bb.y;
  o.z = s.z * ((x.z - mean) * inv) + bb.z;
  o.w = s.w * ((x.w - mean) * inv) + bb.w;
  *(f4*)(out + (size_t)b * D_ + tid * 4) = o;
}

// ---------------- GEMM: C[M,N] = A[M,K] @ W[N,K]^T (+epilogue) ----------------
// 2-phase double-buffered K-loop (T3 minimum): BK=64, LDS 64 KB (2 blocks/CU).
// Next tile's global_load_lds issued BEFORE computing current tile, one barrier
// per K-tile -> HBM latency hides under 32 MFMAs.
#define EP_QKV 0
#define EP_RES 1
#define EP_GELU 2

template <int MODE>
__global__ __launch_bounds__(256, 2) void gemm_kernel(
    const unsigned short* __restrict__ A,
    const unsigned short* __restrict__ Bq,
    const unsigned short* __restrict__ Bk,
    const unsigned short* __restrict__ Bv,
    const float* __restrict__ bias,
    float* __restrict__ hres,
    unsigned short* __restrict__ out0,
    unsigned short* __restrict__ out1,
    unsigned short* __restrict__ out2,
    int N, int K) {
  __shared__ __attribute__((aligned(16))) unsigned short As[2][128 * 64];
  __shared__ __attribute__((aligned(16))) unsigned short Bs[2][128 * 64];
  const int tid = threadIdx.x;
  const int wv = tid >> 6, lane = tid & 63;
  const int quad = lane >> 4, l16 = lane & 15;
  const int bm0 = blockIdx.x * 128;
  int bn0;
  const unsigned short* Bw;
  unsigned short* qout = out0;
  if (MODE == EP_QKV) {
    int sel = blockIdx.y >> 3;
    bn0 = (blockIdx.y & 7) * 128;
    Bw = (sel == 0) ? Bq : ((sel == 1) ? Bk : Bv);
    qout = (sel == 0) ? out0 : ((sel == 1) ? out1 : out2);
  } else {
    bn0 = blockIdx.y * 128;
    Bw = Bq;
  }
  const int wm = (wv & 1) * 64, wn = (wv >> 1) * 64;

  f4 acc[4][4] = {};

  const int nkt = K >> 6;  // K-tiles of 64

  // stage K-tile t into buffer buf: 128 rows x 64 cols bf16 (16 KB each of A,B)
  // source pre-swizzled (c8 ^ row) so linear LDS dest + swizzled read match.
  auto STAGE = [&](int buf, int t) {
    const int k0 = t << 6;
#pragma unroll
    for (int i = 0; i < 4; i++) {
      int c = i * 256 + tid;
      int row = c >> 3;
      int c8 = (c & 7) ^ (row & 7);
      GLOAD16(A + (size_t)(bm0 + row) * K + k0 + c8 * 8,
              (char*)As[buf] + (i * 256 + wv * 64) * 16);
      GLOAD16(Bw + (size_t)(bn0 + row) * K + k0 + c8 * 8,
              (char*)Bs[buf] + (i * 256 + wv * 64) * 16);
    }
  };

  STAGE(0, 0);
  __syncthreads();  // compiler emits vmcnt(0) drain before barrier
  int cur = 0;
  for (int t = 0; t < nkt; t++) {
    if (t + 1 < nkt) STAGE(cur ^ 1, t + 1);  // prefetch next tile (issue-early)
#pragma unroll
    for (int ks = 0; ks < 2; ks++) {
      short8 af[4], bfr[4];
#pragma unroll
      for (int mt = 0; mt < 4; mt++) {
        int row = wm + mt * 16 + l16;
        af[mt] = *(const short8*)(As[cur] + row * 64 + (((ks * 4 + quad) ^ (row & 7)) * 8));
      }
#pragma unroll
      for (int nt = 0; nt < 4; nt++) {
        int row = wn + nt * 16 + l16;
        bfr[nt] = *(const short8*)(Bs[cur] + row * 64 + (((ks * 4 + quad) ^ (row & 7)) * 8));
      }
#pragma unroll
      for (int mt = 0; mt < 4; mt++)
#pragma unroll
        for (int nt = 0; nt < 4; nt++)
          acc[mt][nt] = __builtin_amdgcn_mfma_f32_16x16x32_bf16(af[mt], bfr[nt], acc[mt][nt], 0, 0, 0);
    }
    __syncthreads();  // waits vmcnt(0): next tile resident; buf[cur] reads done
    cur ^= 1;
  }

#pragma unroll
  for (int mt = 0; mt < 4; mt++) {
#pragma unroll
    for (int nt = 0; nt < 4; nt++) {
#pragma unroll
      for (int r = 0; r < 4; r++) {
        int gm = bm0 + wm + mt * 16 + quad * 4 + r;
        int gn = bn0 + wn + nt * 16 + l16;
        float val = acc[mt][nt][r];
        if (MODE == EP_QKV) {
          int b = gm >> 11, t = gm & (T_ - 1);
          int hh = gn >> 6, hd = gn & 63;
          qout[(size_t)((b * H_ + hh) * T_ + t) * HD_ + hd] = f2bf(val);
        } else if (MODE == EP_RES) {
          size_t idx = (size_t)gm * D_ + gn;
          hres[idx] += val + bias[gn];
        } else {  // EP_GELU
          float xg = val + bias[gn];
          float z = 0.7978845608028654f * (xg + 0.044715f * xg * xg * xg);
          float e = __expf(2.0f * z);
          float th = 1.0f - 2.0f / (e + 1.0f);
          out0[(size_t)gm * DFF_ + gn] = f2bf(0.5f * xg * (1.0f + th));
        }
      }
    }
  }
}

// ---------------- V transpose: [B,H,T,HD] -> [B,H,HD,T] ----------------
__global__ __launch_bounds__(256) void vtrans_kernel(const unsigned short* __restrict__ v,
                                                     unsigned short* __restrict__ vt) {
  __shared__ __attribute__((aligned(16))) unsigned short tile[64 * 72];
  const int tid = threadIdx.x;
  const int t0 = blockIdx.x * 64;
  const size_t bh = (size_t)(blockIdx.z * H_ + blockIdx.y);
  const unsigned short* vp = v + bh * T_ * HD_;
#pragma unroll
  for (int i = 0; i < 2; i++) {
    int c = i * 256 + tid;
    int row = c >> 3, c8 = c & 7;
    *(short8*)(tile + row * 72 + c8 * 8) =
        *(const short8*)(vp + (size_t)(t0 + row) * HD_ + c8 * 8);
  }
  __syncthreads();
  unsigned short* op = vt + bh * (size_t)HD_ * T_;
#pragma unroll
  for (int i = 0; i < 2; i++) {
    int c = i * 256 + tid;
    int drow = c >> 3, c8 = c & 7;
    short8 o;
#pragma unroll
    for (int j = 0; j < 8; j++) o[j] = (short)tile[(c8 * 8 + j) * 72 + drow];
    *(short8*)(op + (size_t)drow * T_ + t0 + c8 * 8) = o;
  }
}

// ---------------- flash attention (causal), MFMA, paired q-tiles ----------------
#define ATTN_STEP(QF0, QF1, OF, MR, LR, QT)                                        \
  {                                                                                \
    float sv[4][4];                                                                \
    _Pragma("unroll") for (int nt = 0; nt < 4; nt++) {                             \
      int row = nt * 16 + l16;                                                     \
      int p0 = (quad ^ (row & 7)) * 8;                                             \
      int p1 = ((4 + quad) ^ (row & 7)) * 8;                                       \
      short8 kf0 = *(const short8*)(Ks + row * 64 + p0);                           \
      short8 kf1 = *(const short8*)(Ks + row * 64 + p1);                           \
      f4 z = {};                                                                   \
      z = __builtin_amdgcn_mfma_f32_16x16x32_bf16(QF0, kf0, z, 0, 0, 0);           \
      z = __builtin_amdgcn_mfma_f32_16x16x32_bf16(QF1, kf1, z, 0, 0, 0);           \
      _Pragma("unroll") for (int r = 0; r < 4; r++) {                              \
        float s = z[r] * 0.125f;                                                   \
        if (kt == (QT)) {                                                          \
          int col = kb + nt * 16 + l16;                                            \
          int rowg = (QT) * 64 + wv * 16 + quad * 4 + r;                           \
          if (col > rowg) s = -1e30f;                                              \
        }                                                                          \
        sv[nt][r] = s;                                                             \
      }                                                                            \
    }                                                                              \
    float mnew[4], alpha[4];                                                       \
    _Pragma("unroll") for (int r = 0; r < 4; r++) {                                \
      float mx = fmaxf(fmaxf(sv[0][r], sv[1][r]), fmaxf(sv[2][r], sv[3][r]));      \
      mx = fmaxf(mx, __shfl_xor(mx, 1));                                           \
      mx = fmaxf(mx, __shfl_xor(mx, 2));                                           \
      mx = fmaxf(mx, __shfl_xor(mx, 4));                                           \
      mx = fmaxf(mx, __shfl_xor(mx, 8));                                           \
      mnew[r] = fmaxf(MR[r], mx);                                                  \
      alpha[r] = __expf(MR[r] - mnew[r]);                                          \
      MR[r] = mnew[r];                                                             \
    }                                                                              \
    float pv[4][4];                                                                \
    _Pragma("unroll") for (int nt = 0; nt < 4; nt++)                               \
      _Pragma("unroll") for (int r = 0; r < 4; r++)                                \
        pv[nt][r] = __expf(sv[nt][r] - mnew[r]);                                   \
    _Pragma("unroll") for (int r = 0; r < 4; r++) {                                \
      float s = pv[0][r] + pv[1][r] + pv[2][r] + pv[3][r];                         \
      s += __shfl_xor(s, 1);                                                       \
      s += __shfl_xor(s, 2);                                                       \
      s += __shfl_xor(s, 4);                                                       \
      s += __shfl_xor(s, 8);                                                       \
      LR[r] = LR[r] * alpha[r] + s;                                                \
    }                                                                              \
    _Pragma("unroll") for (int nt = 0; nt < 4; nt++) {                             \
      OF[nt][0] *= alpha[0];                                                       \
      OF[nt][1] *= alpha[1];                                                       \
      OF[nt][2] *= alpha[2];                                                       \
      OF[nt][3] *= alpha[3];                                                       \
    }                                                                              \
    _Pragma("unroll") for (int nt = 0; nt < 4; nt++)                               \
      _Pragma("unroll") for (int r = 0; r < 4; r++)                                \
        pw[(quad * 4 + r) * 88 + nt * 16 + l16] = f2bf(pv[nt][r]);                 \
    short8 pf0 = *(const short8*)(pw + l16 * 88 + quad * 8);                       \
    short8 pf1 = *(const short8*)(pw + l16 * 88 + 32 + quad * 8);                  \
    _Pragma("unroll") for (int nt = 0; nt < 4; nt++) {                             \
      int row = nt * 16 + l16;                                                     \
      int p0 = (quad ^ (row & 7)) * 8;                                             \
      int p1 = ((4 + quad) ^ (row & 7)) * 8;                                       \
      short8 vf0 = *(const short8*)(Vs + row * 64 + p0);                           \
      short8 vf1 = *(const short8*)(Vs + row * 64 + p1);                           \
      OF[nt] = __builtin_amdgcn_mfma_f32_16x16x32_bf16(pf0, vf0, OF[nt], 0, 0, 0); \
      OF[nt] = __builtin_amdgcn_mfma_f32_16x16x32_bf16(pf1, vf1, OF[nt], 0, 0, 0); \
    }                                                                              \
  }

// Work-balanced: block bx owns q-tiles (bx, 31-bx) => exactly 33 tile-steps per
// block, 512 uniform blocks (2/CU), K/V tiles staged once and shared by both
// q-tiles while both are active.
__global__ __launch_bounds__(256, 2) void attn_kernel(
    const unsigned short* __restrict__ q,
    const unsigned short* __restrict__ k,
    const unsigned short* __restrict__ vt,
    unsigned short* __restrict__ ctx) {
  __shared__ __attribute__((aligned(16))) unsigned short Ks[64 * 64];
  __shared__ __attribute__((aligned(16))) unsigned short Vs[64 * 64];
  __shared__ __attribute__((aligned(16))) unsigned short Ps[4][16 * 88];
  const int tid = threadIdx.x;
  const int wv = tid >> 6, lane = tid & 63;
  const int quad = lane >> 4, l16 = lane & 15;
  const int bx = blockIdx.x, hh = blockIdx.y, b = blockIdx.z;
  const int qtA = bx, qtB = 31 - bx;  // qtA in [0,16), qtB in [16,32)
  const size_t bh = (size_t)(b * H_ + hh);
  const unsigned short* qp = q + bh * T_ * HD_;
  const unsigned short* kp = k + bh * T_ * HD_;
  const unsigned short* vp = vt + bh * (size_t)HD_ * T_;

  const int qrA = qtA * 64 + wv * 16 + l16;
  const int qrB = qtB * 64 + wv * 16 + l16;
  const short8 qfA0 = *(const short8*)(qp + (size_t)qrA * HD_ + quad * 8);
  const short8 qfA1 = *(const short8*)(qp + (size_t)qrA * HD_ + 32 + quad * 8);
  const short8 qfB0 = *(const short8*)(qp + (size_t)qrB * HD_ + quad * 8);
  const short8 qfB1 = *(const short8*)(qp + (size_t)qrB * HD_ + 32 + quad * 8);

  f4 ofA[4] = {}, ofB[4] = {};
  float mA[4] = {-1e30f, -1e30f, -1e30f, -1e30f}, lA[4] = {0.f, 0.f, 0.f, 0.f};
  float mB[4] = {-1e30f, -1e30f, -1e30f, -1e30f}, lB[4] = {0.f, 0.f, 0.f, 0.f};
  unsigned short* pw = Ps[wv];

  const int nkt = qtB + 1;
  for (int kt = 0; kt < nkt; kt++) {
    const int kb = kt * 64;
#pragma unroll
    for (int i = 0; i < 2; i++) {
      int c = i * 256 + tid;
      int row = c >> 3;
      int c8 = (c & 7) ^ (row & 7);
      GLOAD16(kp + (size_t)(kb + row) * HD_ + c8 * 8, (char*)Ks + (i * 256 + wv * 64) * 16);
      GLOAD16(vp + (size_t)row * T_ + kb + c8 * 8, (char*)Vs + (i * 256 + wv * 64) * 16);
    }
    __syncthreads();
    ATTN_STEP(qfB0, qfB1, ofB, mB, lB, qtB);
    if (kt <= qtA) ATTN_STEP(qfA0, qfA1, ofA, mA, lA, qtA);
    __syncthreads();
  }
#pragma unroll
  for (int nt = 0; nt < 4; nt++) {
#pragma unroll
    for (int r = 0; r < 4; r++) {
      int dcol = hh * HD_ + nt * 16 + l16;
      int rowgB = qtB * 64 + wv * 16 + quad * 4 + r;
      ctx[(size_t)(b * T_ + rowgB) * D_ + dcol] = f2bf(ofB[nt][r] / lB[r]);
      int rowgA = qtA * 64 + wv * 16 + quad * 4 + r;
      ctx[(size_t)(b * T_ + rowgA) * D_ + dcol] = f2bf(ofA[nt][r] / lA[r]);
    }
  }
}

// ---------------- logits GEMV: out[b,v] = hln[b,:] . Wemb[v,:] ----------------
__global__ __launch_bounds__(256) void logits_kernel(const float* __restrict__ wemb,
    const float* __restrict__ hln, float* __restrict__ out) {
  const int tid = threadIdx.x;
  const int wv = tid >> 6, lane = tid & 63;
  const int rbase = blockIdx.x * 32 + wv * 8;
  f4 h0[4], h1[4];
#pragma unroll
  for (int j = 0; j < 4; j++) {
    h0[j] = *(const f4*)(hln + j * 256 + lane * 4);
    h1[j] = *(const f4*)(hln + D_ + j * 256 + lane * 4);
  }
#pragma unroll
  for (int i = 0; i < 8; i++) {
    int r = rbase + i;
    if (r >= V_) return;
    const float* wr = wemb + (size_t)r * D_;
    float a0 = 0.f, a1 = 0.f;
#pragma unroll
    for (int j = 0; j < 4; j++) {
      f4 w4 = *(const f4*)(wr + j * 256 + lane * 4);
      a0 += w4.x * h0[j].x + w4.y * h0[j].y + w4.z * h0[j].z + w4.w * h0[j].w;
      a1 += w4.x * h1[j].x + w4.y * h1[j].y + w4.z * h1[j].z + w4.w * h1[j].w;
    }
#pragma unroll
    for (int off = 32; off > 0; off >>= 1) {
      a0 += __shfl_down(a0, off);
      a1 += __shfl_down(a1, off);
    }
    if (lane == 0) {
      out[r] = a0;
      out[V_ + r] = a1;
    }
  }
}

extern "C" void kernel_launch(void* const* d_in, const int* in_sizes, int n_in,
                              void* d_out, int out_size, void* d_ws, size_t ws_size,
                              hipStream_t stream) {
  (void)in_sizes; (void)n_in; (void)out_size; (void)ws_size;
  const int*   x    = (const int*)  d_in[0];
  const float* Wemb = (const float*)d_in[1];
  const float* pos  = (const float*)d_in[2];
  const float* Wq   = (const float*)d_in[3];
  const float* Wk   = (const float*)d_in[4];
  const float* Wv   = (const float*)d_in[5];
  const float* Wo   = (const float*)d_in[6];
  const float* bo   = (const float*)d_in[7];
  const float* n1s  = (const float*)d_in[8];
  const float* n1b  = (const float*)d_in[9];
  const float* n2s  = (const float*)d_in[10];
  const float* n2b  = (const float*)d_in[11];
  const float* W1   = (const float*)d_in[12];
  const float* b1   = (const float*)d_in[13];
  const float* W2   = (const float*)d_in[14];
  const float* b2   = (const float*)d_in[15];
  const float* fsc  = (const float*)d_in[16];
  const float* fsh  = (const float*)d_in[17];
  float* out = (float*)d_out;

  char* p = (char*)d_ws;
  auto alloc = [&](size_t bytes) -> char* {
    char* r = p;
    p += (bytes + 255) & ~(size_t)255;
    return r;
  };
  unsigned short* wq_b = (unsigned short*)alloc((size_t)L_ * D_ * D_ * 2);
  unsigned short* wk_b = (unsigned short*)alloc((size_t)L_ * D_ * D_ * 2);
  unsigned short* wv_b = (unsigned short*)alloc((size_t)L_ * D_ * D_ * 2);
  unsigned short* wo_b = (unsigned short*)alloc((size_t)L_ * D_ * D_ * 2);
  unsigned short* w1_b = (unsigned short*)alloc((size_t)L_ * DFF_ * D_ * 2);
  unsigned short* w2_b = (unsigned short*)alloc((size_t)L_ * DFF_ * D_ * 2);
  float*          h    = (float*)alloc((size_t)M_ * D_ * 4);
  unsigned short* xn   = (unsigned short*)alloc((size_t)M_ * D_ * 2);
  unsigned short* qb   = (unsigned short*)alloc((size_t)M_ * D_ * 2);
  unsigned short* kb   = (unsigned short*)alloc((size_t)M_ * D_ * 2);
  unsigned short* vb   = (unsigned short*)alloc((size_t)M_ * D_ * 2);
  unsigned short* vtb  = (unsigned short*)alloc((size_t)M_ * D_ * 2);
  unsigned short* ctx  = (unsigned short*)alloc((size_t)M_ * D_ * 2);
  unsigned short* act  = (unsigned short*)alloc((size_t)M_ * DFF_ * 2);
  float*          hln  = (float*)alloc(2 * D_ * 4);

  cvt_kernel<<<2048, 256, 0, stream>>>(Wq, wq_b, L_ * D_ * D_);
  cvt_kernel<<<2048, 256, 0, stream>>>(Wk, wk_b, L_ * D_ * D_);
  cvt_kernel<<<2048, 256, 0, stream>>>(Wv, wv_b, L_ * D_ * D_);
  cvt_kernel<<<2048, 256, 0, stream>>>(Wo, wo_b, L_ * D_ * D_);
  cvt_kernel<<<2048, 256, 0, stream>>>(W1, w1_b, L_ * DFF_ * D_);
  cvt_kernel<<<2048, 256, 0, stream>>>(W2, w2_b, L_ * DFF_ * D_);
  embed_kernel<<<M_, 256, 0, stream>>>(x, Wemb, pos, h);

  for (int l = 0; l < L_; l++) {
    ln_kernel<<<M_, 256, 0, stream>>>(h, n1s + l * D_, n1b + l * D_, xn);
    gemm_kernel<EP_QKV><<<dim3(32, 24), 256, 0, stream>>>(
        xn, wq_b + (size_t)l * D_ * D_, wk_b + (size_t)l * D_ * D_,
        wv_b + (size_t)l * D_ * D_, nullptr, nullptr, qb, kb, vb, D_, D_);
    vtrans_kernel<<<dim3(32, H_, B_), 256, 0, stream>>>(vb, vtb);
    attn_kernel<<<dim3(16, H_, B_), 256, 0, stream>>>(qb, kb, vtb, ctx);
    gemm_kernel<EP_RES><<<dim3(32, 8), 256, 0, stream>>>(
        ctx, wo_b + (size_t)l * D_ * D_, nullptr, nullptr,
        bo + l * D_, h, nullptr, nullptr, nullptr, D_, D_);
    ln_kernel<<<M_, 256, 0, stream>>>(h, n2s + l * D_, n2b + l * D_, xn);
    gemm_kernel<EP_GELU><<<dim3(32, 32), 256, 0, stream>>>(
        xn, w1_b + (size_t)l * DFF_ * D_, nullptr, nullptr,
        b1 + l * DFF_, nullptr, act, nullptr, nullptr, DFF_, D_);
    gemm_kernel<EP_RES><<<dim3(32, 8), 256, 0, stream>>>(
        act, w2_b + (size_t)l * DFF_ * D_, nullptr, nullptr,
        b2 + l * D_, h, nullptr, nullptr, nullptr, D_, DFF_);
  }
  ln_final_kernel<<<2, 256, 0, stream>>>(h, fsc, fsh, hln);
  logits_kernel<<<(V_ + 31) / 32, 256, 0, stream>>>(Wemb, hln, out);
}